// Round 2
// baseline (1413.213 us; speedup 1.0000x reference)
//
#include <hip/hip_runtime.h>
#include <math.h>

// ---------- problem constants ----------
#define BB    16
#define CC    256
#define HH    64
#define WW2   64
#define NHD   8
#define HD    32
#define NT    64      // tokens per window
#define NWIN  1024    // BB * 8 * 8
#define TOK   65536   // BB * HH * WW2
#define HIDN  1024
#define GKS   9
#define GPAD  4

typedef short bf16x8 __attribute__((ext_vector_type(8)));
typedef float f32x4  __attribute__((ext_vector_type(4)));

__device__ __forceinline__ float b2f(unsigned short u) {
    return __uint_as_float(((unsigned int)u) << 16);
}
__device__ __forceinline__ unsigned short f2b(float f) {
    unsigned int x = __float_as_uint(f);
    unsigned int r = x + 0x7fffu + ((x >> 16) & 1u);   // RNE
    return (unsigned short)(r >> 16);
}

// canonical-param element offsets inside PAR (each weight start 64-elem aligned)
#define O_N1G  64
#define O_N1B  320
#define O_QKVW 576
#define O_QKVB 197184
#define O_RPB  197952
#define O_PW   199808
#define O_PB   265344
#define O_GW   265600
#define O_GB   286336
#define O_N2G  286592
#define O_N2B  286848
#define O_W1   287104
#define O_B1   549248
#define O_W2   550272
#define O_B2   812416

struct ParTab {
    const void* src[15];
    int n[15];
    int off[15];
};

// ---------------------------------------------------------------------------
// K0: dtype detector. bf16 N(0,1) data never has exponent >= 140 (|v|>=2^13);
// fp32 misread as ushorts has random exponents in the low halves (~45% wild).
// flag = 1 -> inputs are fp32.
// ---------------------------------------------------------------------------
__global__ __launch_bounds__(256) void k_detect(const unsigned short* __restrict__ x,
                                                int* __restrict__ flag) {
    __shared__ int cnt;
    if (threadIdx.x == 0) cnt = 0;
    __syncthreads();
    const unsigned short u = x[threadIdx.x];
    const int e = (u >> 7) & 0xFF;
    if (e >= 140) atomicAdd(&cnt, 1);
    __syncthreads();
    if (threadIdx.x == 0) *flag = (cnt >= 8) ? 1 : 0;
}

// K0b: canonicalize x -> XC (bf16, same (B,C,H,W) layout)
__global__ __launch_bounds__(256) void k_conv_x(const void* __restrict__ src,
                                                const int* __restrict__ flag,
                                                unsigned short* __restrict__ dst) {
    const int base = (blockIdx.x * 256 + threadIdx.x) * 8;
    if (*flag) {
        const float4* s4 = (const float4*)src;
        const float4 a = s4[base >> 2], b = s4[(base >> 2) + 1];
        unsigned short t[8] = {f2b(a.x), f2b(a.y), f2b(a.z), f2b(a.w),
                               f2b(b.x), f2b(b.y), f2b(b.z), f2b(b.w)};
        *(uint4*)&dst[base] = *(const uint4*)t;
    } else {
        *(uint4*)&dst[base] = ((const uint4*)src)[base >> 3];
    }
}

// K0c: canonicalize the 15 parameter tensors into PAR
__global__ __launch_bounds__(256) void k_conv_par(ParTab tab,
                                                  const int* __restrict__ flag,
                                                  unsigned short* __restrict__ par) {
    const int t = blockIdx.y;
    const int n = tab.n[t], off = tab.off[t];
    const bool f32 = (*flag != 0);
    for (int i = blockIdx.x * 256 + threadIdx.x; i < n; i += 64 * 256) {
        par[off + i] = f32 ? f2b(((const float*)tab.src[t])[i])
                           : ((const unsigned short*)tab.src[t])[i];
    }
}

// ---------------------------------------------------------------------------
// Shared 64x64-tile MFMA GEMM core: C[m][n] = sum_k A[m][k] * B[n][k]
// ---------------------------------------------------------------------------
template <int KDIM, typename Epi>
__device__ __forceinline__ void gemm64(const unsigned short* __restrict__ A,
                                       const unsigned short* __restrict__ Bw,
                                       Epi epi) {
    __shared__ __align__(16) unsigned short As[64 * 64];
    __shared__ __align__(16) unsigned short Bs[64 * 64];
    const int tid = threadIdx.x;
    const int wv = tid >> 6, ln = tid & 63;
    const int m0 = blockIdx.x * 64, n0 = blockIdx.y * 64;

    f32x4 acc[4] = {};

    for (int kb = 0; kb < KDIM; kb += 64) {
        for (int idx = tid; idx < 512; idx += 256) {
            const int row = idx >> 3, c8 = (idx & 7) * 8;
            *(uint4*)&As[row * 64 + c8] =
                *(const uint4*)&A[(size_t)(m0 + row) * KDIM + kb + c8];
            *(uint4*)&Bs[row * 64 + c8] =
                *(const uint4*)&Bw[(size_t)(n0 + row) * KDIM + kb + c8];
        }
        __syncthreads();
#pragma unroll
        for (int ks = 0; ks < 2; ++ks) {
            const bf16x8 a =
                *(const bf16x8*)&As[(16 * wv + (ln & 15)) * 64 + ks * 32 + (ln >> 4) * 8];
#pragma unroll
            for (int f = 0; f < 4; ++f) {
                const bf16x8 b =
                    *(const bf16x8*)&Bs[(f * 16 + (ln & 15)) * 64 + ks * 32 + (ln >> 4) * 8];
                acc[f] = __builtin_amdgcn_mfma_f32_16x16x32_bf16(a, b, acc[f], 0, 0, 0);
            }
        }
        __syncthreads();
    }
#pragma unroll
    for (int f = 0; f < 4; ++f)
#pragma unroll
        for (int r = 0; r < 4; ++r) {
            const int m = m0 + 16 * wv + (ln >> 4) * 4 + r;
            const int n = n0 + f * 16 + (ln & 15);
            epi(m, n, acc[f][r]);
        }
}

// ---------------------------------------------------------------------------
// K1: LayerNorm1 + window partition.  XC:(B,C,H,W) -> XN:(win,n,C)
// ---------------------------------------------------------------------------
__global__ __launch_bounds__(256) void k_ln1(const unsigned short* __restrict__ x,
                                             const unsigned short* __restrict__ g,
                                             const unsigned short* __restrict__ bt,
                                             unsigned short* __restrict__ XN) {
    __shared__ __align__(16) unsigned short xs[256 * 65];
    __shared__ float ps[4][64], ps2[4][64];
    __shared__ float mean_s[64], rstd_s[64];
    const int tid = threadIdx.x;
    const int win = blockIdx.x;
    const int b = win >> 6, wh = (win >> 3) & 7, ww = win & 7;

    for (int idx = tid; idx < 16384; idx += 256) {
        const int c = idx >> 6, n = idx & 63;
        const int h = wh * 8 + (n >> 3), w = ww * 8 + (n & 7);
        xs[c * 65 + n] = x[((size_t)(b * CC + c) * HH + h) * WW2 + w];
    }
    __syncthreads();
    {
        const int tok = tid & 63, part = tid >> 6;
        float s = 0.f, s2 = 0.f;
        for (int c = part * 64; c < part * 64 + 64; ++c) {
            const float v = b2f(xs[c * 65 + tok]);
            s += v; s2 += v * v;
        }
        ps[part][tok] = s; ps2[part][tok] = s2;
    }
    __syncthreads();
    if (tid < 64) {
        const float s  = ps[0][tid] + ps[1][tid] + ps[2][tid] + ps[3][tid];
        const float s2 = ps2[0][tid] + ps2[1][tid] + ps2[2][tid] + ps2[3][tid];
        const float mean = s * (1.f / 256.f);
        const float var  = s2 * (1.f / 256.f) - mean * mean;
        mean_s[tid] = mean;
        rstd_s[tid] = rsqrtf(var + 1e-5f);
    }
    __syncthreads();
    for (int idx = tid; idx < 16384; idx += 256) {
        const int n = idx >> 8, c = idx & 255;
        const float v = (b2f(xs[c * 65 + n]) - mean_s[n]) * rstd_s[n] * b2f(g[c]) + b2f(bt[c]);
        XN[(size_t)(win * NT + n) * CC + c] = f2b(v);
    }
}

// ---------------------------------------------------------------------------
// K2: QKV GEMM -> Q(scaled),K,V  layout [win][head][n][hd]
// ---------------------------------------------------------------------------
__global__ __launch_bounds__(256) void k_gemm_qkv(const unsigned short* __restrict__ XN,
                                                  const unsigned short* __restrict__ Wq,
                                                  const unsigned short* __restrict__ bq,
                                                  unsigned short* __restrict__ Q,
                                                  unsigned short* __restrict__ K,
                                                  unsigned short* __restrict__ V) {
    gemm64<256>(XN, Wq, [&](int m, int n, float v) {
        v += b2f(bq[n]);
        const int three = n >> 8, rem = n & 255, head = rem >> 5, d = rem & 31;
        if (three == 0) v *= 4.0f;   // qk_scale
        unsigned short* dst = (three == 0) ? Q : ((three == 1) ? K : V);
        const int win = m >> 6, nt = m & 63;
        dst[((size_t)(win * NHD + head) * NT + nt) * HD + d] = f2b(v);
    });
}

// ---------------------------------------------------------------------------
// K3: window attention (block per (window, head)); register softmax
// ---------------------------------------------------------------------------
__global__ __launch_bounds__(256) void k_attn(const unsigned short* __restrict__ Q,
                                              const unsigned short* __restrict__ K,
                                              const unsigned short* __restrict__ V,
                                              const unsigned short* __restrict__ rpb,
                                              unsigned short* __restrict__ AO) {
    __shared__ __align__(16) unsigned short Pb[64 * 72];
    __shared__ __align__(16) unsigned short Vt[32 * 72];
    const int tid = threadIdx.x, wv = tid >> 6, ln = tid & 63;
    const int win = blockIdx.x, head = blockIdx.y;
    const size_t base = (size_t)(win * NHD + head) * NT * HD;
    const unsigned short* Qb = Q + base;
    const unsigned short* Kb = K + base;
    const unsigned short* Vb = V + base;

    for (int idx = tid; idx < 2048; idx += 256)
        Vt[(idx & 31) * 72 + (idx >> 5)] = Vb[idx];   // V transposed [d][tok]

    // S = Q K^T   (hd = 32 = one MFMA K-step)
    const bf16x8 a = *(const bf16x8*)&Qb[(16 * wv + (ln & 15)) * HD + (ln >> 4) * 8];
    f32x4 accs[4] = {};
#pragma unroll
    for (int f = 0; f < 4; ++f) {
        const bf16x8 b = *(const bf16x8*)&Kb[(f * 16 + (ln & 15)) * HD + (ln >> 4) * 8];
        accs[f] = __builtin_amdgcn_mfma_f32_16x16x32_bf16(a, b, accs[f], 0, 0, 0);
    }
    // + relative position bias (closed-form index)
    const int qloc = (ln >> 4) * 4;
#pragma unroll
    for (int f = 0; f < 4; ++f)
#pragma unroll
        for (int r = 0; r < 4; ++r) {
            const int rr = 16 * wv + qloc + r;
            const int cth = f * 16 + (ln & 15);
            const int bidx = ((rr >> 3) - (cth >> 3) + 7) * 15 + ((rr & 7) - (cth & 7) + 7);
            accs[f][r] += b2f(rpb[bidx * NHD + head]);
        }
    // softmax per query row: reduce over lanes sharing (ln>>4), i.e. low-4-bit hypercube
#pragma unroll
    for (int r = 0; r < 4; ++r) {
        float m = fmaxf(fmaxf(accs[0][r], accs[1][r]), fmaxf(accs[2][r], accs[3][r]));
#pragma unroll
        for (int o = 1; o <= 8; o <<= 1) m = fmaxf(m, __shfl_xor(m, o));
        float p[4], s = 0.f;
#pragma unroll
        for (int f = 0; f < 4; ++f) { p[f] = expf(accs[f][r] - m); s += p[f]; }
#pragma unroll
        for (int o = 1; o <= 8; o <<= 1) s += __shfl_xor(s, o);
        const float inv = 1.f / s;
#pragma unroll
        for (int f = 0; f < 4; ++f)
            Pb[(16 * wv + qloc + r) * 72 + f * 16 + (ln & 15)] = f2b(p[f] * inv);
    }
    __syncthreads();   // covers both Pb and Vt

    // O = P V
    f32x4 acco[2] = {};
#pragma unroll
    for (int kb = 0; kb < 64; kb += 32) {
        const bf16x8 ap = *(const bf16x8*)&Pb[(16 * wv + (ln & 15)) * 72 + kb + (ln >> 4) * 8];
#pragma unroll
        for (int f = 0; f < 2; ++f) {
            const bf16x8 bv = *(const bf16x8*)&Vt[(f * 16 + (ln & 15)) * 72 + kb + (ln >> 4) * 8];
            acco[f] = __builtin_amdgcn_mfma_f32_16x16x32_bf16(ap, bv, acco[f], 0, 0, 0);
        }
    }
#pragma unroll
    for (int f = 0; f < 2; ++f)
#pragma unroll
        for (int r = 0; r < 4; ++r) {
            const int rr = 16 * wv + qloc + r;
            const int d = f * 16 + (ln & 15);
            AO[(size_t)(win * NT + rr) * CC + head * HD + d] = f2b(acco[f][r]);
        }
}

// ---------------------------------------------------------------------------
// K4: gaze branch (fold -> depthwise 9x9 -> unfold), accumulate into AO
// ---------------------------------------------------------------------------
__global__ __launch_bounds__(256) void k_gaze(const unsigned short* __restrict__ V,
                                              const unsigned short* __restrict__ gw,
                                              const unsigned short* __restrict__ gb,
                                              unsigned short* __restrict__ AO) {
    const int ch = threadIdx.x;
    const int cpix = blockIdx.x, r = blockIdx.y, b = blockIdx.z;
    const int head = ch >> 5, d = ch & 31;
    float acc = 0.f;
#pragma unroll
    for (int dy = 0; dy < GKS; ++dy) {
        const int rp = r + dy - GPAD;
        if (rp < 0 || rp >= HH) continue;
#pragma unroll
        for (int dx = 0; dx < GKS; ++dx) {
            const int cp = cpix + dx - GPAD;
            if (cp < 0 || cp >= WW2) continue;
            const int win = b * 64 + (rp & 7) * 8 + (cp & 7);
            const int n = (rp >> 3) * 8 + (cp >> 3);
            acc += b2f(V[((size_t)(win * NHD + head) * NT + n) * HD + d]) *
                   b2f(gw[(dy * GKS + dx) * CC + ch]);
        }
    }
    const int win0 = b * 64 + (r & 7) * 8 + (cpix & 7);
    const int n0 = (r >> 3) * 8 + (cpix >> 3);
    const size_t o = (size_t)(win0 * NT + n0) * CC + ch;
    AO[o] = f2b(b2f(AO[o]) + acc + b2f(gb[ch]));
}

// ---------------------------------------------------------------------------
// K5: proj GEMM + shortcut residual -> X2 (bf16, windowed order)
// shortcut read straight from XC via fold index algebra
// ---------------------------------------------------------------------------
__global__ __launch_bounds__(256) void k_gemm_proj(const unsigned short* __restrict__ AO,
                                                   const unsigned short* __restrict__ Wp,
                                                   const unsigned short* __restrict__ bp,
                                                   const unsigned short* __restrict__ XC,
                                                   unsigned short* __restrict__ X2) {
    gemm64<256>(AO, Wp, [&](int m, int n, float v) {
        const int win = m >> 6, nt = m & 63;
        const int b = win >> 6, wh = (win >> 3) & 7, ww = win & 7;
        const int h = wh * 8 + (nt >> 3), w = ww * 8 + (nt & 7);
        v += b2f(bp[n]) + b2f(XC[((size_t)(b * CC + n) * HH + h) * WW2 + w]);
        X2[(size_t)m * CC + n] = f2b(v);
    });
}

// ---------------------------------------------------------------------------
// K6: LayerNorm2 (wave per token)
// ---------------------------------------------------------------------------
__global__ __launch_bounds__(256) void k_ln2(const unsigned short* __restrict__ X2,
                                             const unsigned short* __restrict__ g,
                                             const unsigned short* __restrict__ bt,
                                             unsigned short* __restrict__ X2N) {
    const int wv = threadIdx.x >> 6, ln = threadIdx.x & 63;
    const int t = blockIdx.x * 4 + wv;
    float vals[4];
    float s = 0.f, s2 = 0.f;
#pragma unroll
    for (int k = 0; k < 4; ++k) {
        const float v = b2f(X2[(size_t)t * CC + k * 64 + ln]);
        vals[k] = v; s += v; s2 += v * v;
    }
#pragma unroll
    for (int off = 32; off; off >>= 1) {
        s += __shfl_xor(s, off);
        s2 += __shfl_xor(s2, off);
    }
    const float mean = s * (1.f / 256.f);
    const float rstd = rsqrtf(s2 * (1.f / 256.f) - mean * mean + 1e-5f);
#pragma unroll
    for (int k = 0; k < 4; ++k) {
        const int c = k * 64 + ln;
        X2N[(size_t)t * CC + c] = f2b((vals[k] - mean) * rstd * b2f(g[c]) + b2f(bt[c]));
    }
}

// ---------------------------------------------------------------------------
// K7: fc1 GEMM + exact GELU -> H1
// ---------------------------------------------------------------------------
__global__ __launch_bounds__(256) void k_gemm_fc1(const unsigned short* __restrict__ X2N,
                                                  const unsigned short* __restrict__ W1,
                                                  const unsigned short* __restrict__ b1,
                                                  unsigned short* __restrict__ H1) {
    gemm64<256>(X2N, W1, [&](int m, int n, float v) {
        v += b2f(b1[n]);
        const float gl = 0.5f * v * (1.0f + erff(v * 0.70710678118654752f));
        H1[(size_t)m * HIDN + n] = f2b(gl);
    });
}

// ---------------------------------------------------------------------------
// K8: fc2 GEMM + trunk residual -> XOUT (windowed order)
// ---------------------------------------------------------------------------
__global__ __launch_bounds__(256) void k_gemm_fc2(const unsigned short* __restrict__ H1,
                                                  const unsigned short* __restrict__ W2,
                                                  const unsigned short* __restrict__ b2v,
                                                  const unsigned short* __restrict__ X2,
                                                  unsigned short* __restrict__ XOUT) {
    gemm64<1024>(H1, W2, [&](int m, int n, float v) {
        v += b2f(b2v[n]) + b2f(X2[(size_t)m * CC + n]);
        XOUT[(size_t)m * CC + n] = f2b(v);
    });
}

// ---------------------------------------------------------------------------
// K9: window reverse + transpose to (B,C,H,W); dtype-flagged output store
// ---------------------------------------------------------------------------
__global__ __launch_bounds__(256) void k_out(const unsigned short* __restrict__ XOUT,
                                             const int* __restrict__ flag,
                                             void* __restrict__ out) {
    __shared__ __align__(16) unsigned short ys[64 * 257];
    const int tid = threadIdx.x;
    const int win = blockIdx.x;
    const int b = win >> 6, wh = (win >> 3) & 7, ww = win & 7;
    for (int idx = tid; idx < 16384; idx += 256) {
        const int n = idx >> 8, c = idx & 255;
        ys[n * 257 + c] = XOUT[(size_t)(win * NT + n) * CC + c];
    }
    __syncthreads();
    const bool f32 = (*flag != 0);
    for (int idx = tid; idx < 16384; idx += 256) {
        const int ch = idx >> 6, n = idx & 63;
        const int h = wh * 8 + (n >> 3), w = ww * 8 + (n & 7);
        const size_t o = ((size_t)(b * CC + ch) * HH + h) * WW2 + w;
        const unsigned short v = ys[n * 257 + ch];
        if (f32) ((float*)out)[o] = b2f(v);
        else     ((unsigned short*)out)[o] = v;
    }
}

// ---------------------------------------------------------------------------
extern "C" void kernel_launch(void* const* d_in, const int* in_sizes, int n_in,
                              void* d_out, int out_size, void* d_ws, size_t ws_size,
                              hipStream_t stream) {
    // workspace layout (226 MiB total):
    //   [0,    32M)  XC  (canonical bf16 x)         alive through proj
    //   [32M,  64M)  XN -> X2N -> XOUT
    //   [64M,  96M)  Q    ┐
    //   [96M, 128M)  K    │  H1 (128M) overlays [64M,192M) after all are dead
    //   [128M,160M)  V    │
    //   [160M,192M)  AO   ┘
    //   [192M,224M)  X2 (bf16 trunk)
    //   [224M,226M)  PAR (flag int + canonical bf16 params)
    char* ws = (char*)d_ws;
    const size_t MB = 1048576;
    unsigned short* XC  = (unsigned short*)(ws);
    unsigned short* XN  = (unsigned short*)(ws + 32 * MB);
    unsigned short* Qb  = (unsigned short*)(ws + 64 * MB);
    unsigned short* Kb  = (unsigned short*)(ws + 96 * MB);
    unsigned short* Vb  = (unsigned short*)(ws + 128 * MB);
    unsigned short* AO  = (unsigned short*)(ws + 160 * MB);
    unsigned short* H1  = (unsigned short*)(ws + 64 * MB);
    unsigned short* X2  = (unsigned short*)(ws + 192 * MB);
    unsigned short* PAR = (unsigned short*)(ws + 224 * MB);
    int* FLAG = (int*)(ws + 224 * MB);
    unsigned short* X2N  = XN;
    unsigned short* XOUT = XN;

    ParTab tab;
    const int srcidx[15] = {3, 4, 5, 6, 7, 8, 9, 10, 11, 12, 13, 14, 15, 16, 17};
    const int sizes[15]  = {256, 256, 196608, 768, 1800, 65536, 256, 20736, 256,
                            256, 256, 262144, 1024, 262144, 256};
    const int offs[15]   = {O_N1G, O_N1B, O_QKVW, O_QKVB, O_RPB, O_PW, O_PB, O_GW, O_GB,
                            O_N2G, O_N2B, O_W1, O_B1, O_W2, O_B2};
    for (int i = 0; i < 15; ++i) {
        tab.src[i] = d_in[srcidx[i]];
        tab.n[i] = sizes[i];
        tab.off[i] = offs[i];
    }

    k_detect  <<<1,                 256, 0, stream>>>((const unsigned short*)d_in[2], FLAG);
    k_conv_x  <<<8192,              256, 0, stream>>>(d_in[2], FLAG, XC);
    k_conv_par<<<dim3(64, 15),      256, 0, stream>>>(tab, FLAG, PAR);
    k_ln1     <<<NWIN,              256, 0, stream>>>(XC, PAR + O_N1G, PAR + O_N1B, XN);
    k_gemm_qkv<<<dim3(1024, 12),    256, 0, stream>>>(XN, PAR + O_QKVW, PAR + O_QKVB, Qb, Kb, Vb);
    k_attn    <<<dim3(NWIN, NHD),   256, 0, stream>>>(Qb, Kb, Vb, PAR + O_RPB, AO);
    k_gaze    <<<dim3(WW2, HH, BB), 256, 0, stream>>>(Vb, PAR + O_GW, PAR + O_GB, AO);
    k_gemm_proj<<<dim3(1024, 4),    256, 0, stream>>>(AO, PAR + O_PW, PAR + O_PB, XC, X2);
    k_ln2     <<<TOK / 4,           256, 0, stream>>>(X2, PAR + O_N2G, PAR + O_N2B, X2N);
    k_gemm_fc1<<<dim3(1024, 16),    256, 0, stream>>>(X2N, PAR + O_W1, PAR + O_B1, H1);
    k_gemm_fc2<<<dim3(1024, 4),     256, 0, stream>>>(H1, PAR + O_W2, PAR + O_B2, X2, XOUT);
    k_out     <<<NWIN,              256, 0, stream>>>(XOUT, FLAG, d_out);
}

// Round 3
// 761.675 us; speedup vs baseline: 1.8554x; 1.8554x over previous
//
#include <hip/hip_runtime.h>
#include <math.h>

// ---------- problem constants ----------
#define BB    16
#define CC    256
#define HH    64
#define WW2   64
#define NHD   8
#define HD    32
#define NT    64      // tokens per window
#define NWIN  1024    // BB * 8 * 8
#define TOK   65536   // BB * HH * WW2
#define HIDN  1024
#define GKS   9
#define GPAD  4

typedef short bf16x8 __attribute__((ext_vector_type(8)));
typedef float f32x4  __attribute__((ext_vector_type(4)));

__device__ __forceinline__ float b2f(unsigned short u) {
    return __uint_as_float(((unsigned int)u) << 16);
}
__device__ __forceinline__ unsigned short f2b(float f) {
    unsigned int x = __float_as_uint(f);
    unsigned int r = x + 0x7fffu + ((x >> 16) & 1u);   // RNE
    return (unsigned short)(r >> 16);
}

// canonical-param element offsets inside PAR (each weight start 64-elem aligned)
#define O_N1G  64
#define O_N1B  320
#define O_QKVW 576
#define O_QKVB 197184
#define O_RPB  197952
#define O_PW   199808
#define O_PB   265344
#define O_GW   265600
#define O_GB   286336
#define O_N2G  286592
#define O_N2B  286848
#define O_W1   287104
#define O_B1   549248
#define O_W2   550272
#define O_B2   812416

struct ParTab {
    const void* src[15];
    int n[15];
    int off[15];
};

// ---------------------------------------------------------------------------
// K0: dtype detector (inputs proved fp32 in round 2; keep the hedge, it's 2 µs)
// ---------------------------------------------------------------------------
__global__ __launch_bounds__(256) void k_detect(const unsigned short* __restrict__ x,
                                                int* __restrict__ flag) {
    __shared__ int cnt;
    if (threadIdx.x == 0) cnt = 0;
    __syncthreads();
    const unsigned short u = x[threadIdx.x];
    const int e = (u >> 7) & 0xFF;
    if (e >= 140) atomicAdd(&cnt, 1);
    __syncthreads();
    if (threadIdx.x == 0) *flag = (cnt >= 8) ? 1 : 0;
}

// K0b: canonicalize x -> XC (bf16, same (B,C,H,W) layout)
__global__ __launch_bounds__(256) void k_conv_x(const void* __restrict__ src,
                                                const int* __restrict__ flag,
                                                unsigned short* __restrict__ dst) {
    const int base = (blockIdx.x * 256 + threadIdx.x) * 8;
    if (*flag) {
        const float4* s4 = (const float4*)src;
        const float4 a = s4[base >> 2], b = s4[(base >> 2) + 1];
        unsigned short t[8] = {f2b(a.x), f2b(a.y), f2b(a.z), f2b(a.w),
                               f2b(b.x), f2b(b.y), f2b(b.z), f2b(b.w)};
        *(uint4*)&dst[base] = *(const uint4*)t;
    } else {
        *(uint4*)&dst[base] = ((const uint4*)src)[base >> 3];
    }
}

// K0c: canonicalize the 15 parameter tensors into PAR
__global__ __launch_bounds__(256) void k_conv_par(ParTab tab,
                                                  const int* __restrict__ flag,
                                                  unsigned short* __restrict__ par) {
    const int t = blockIdx.y;
    const int n = tab.n[t], off = tab.off[t];
    const bool f32 = (*flag != 0);
    for (int i = blockIdx.x * 256 + threadIdx.x; i < n; i += 64 * 256) {
        par[off + i] = f32 ? f2b(((const float*)tab.src[t])[i])
                           : ((const unsigned short*)tab.src[t])[i];
    }
}

// ---------------------------------------------------------------------------
// Shared 64x64-tile MFMA GEMM core: C[m][n] = sum_k A[m][k] * B[n][k]
// ---------------------------------------------------------------------------
template <int KDIM, typename Epi>
__device__ __forceinline__ void gemm64(const unsigned short* __restrict__ A,
                                       const unsigned short* __restrict__ Bw,
                                       Epi epi) {
    __shared__ __align__(16) unsigned short As[64 * 64];
    __shared__ __align__(16) unsigned short Bs[64 * 64];
    const int tid = threadIdx.x;
    const int wv = tid >> 6, ln = tid & 63;
    const int m0 = blockIdx.x * 64, n0 = blockIdx.y * 64;

    f32x4 acc[4] = {};

    for (int kb = 0; kb < KDIM; kb += 64) {
        for (int idx = tid; idx < 512; idx += 256) {
            const int row = idx >> 3, c8 = (idx & 7) * 8;
            *(uint4*)&As[row * 64 + c8] =
                *(const uint4*)&A[(size_t)(m0 + row) * KDIM + kb + c8];
            *(uint4*)&Bs[row * 64 + c8] =
                *(const uint4*)&Bw[(size_t)(n0 + row) * KDIM + kb + c8];
        }
        __syncthreads();
#pragma unroll
        for (int ks = 0; ks < 2; ++ks) {
            const bf16x8 a =
                *(const bf16x8*)&As[(16 * wv + (ln & 15)) * 64 + ks * 32 + (ln >> 4) * 8];
#pragma unroll
            for (int f = 0; f < 4; ++f) {
                const bf16x8 b =
                    *(const bf16x8*)&Bs[(f * 16 + (ln & 15)) * 64 + ks * 32 + (ln >> 4) * 8];
                acc[f] = __builtin_amdgcn_mfma_f32_16x16x32_bf16(a, b, acc[f], 0, 0, 0);
            }
        }
        __syncthreads();
    }
#pragma unroll
    for (int f = 0; f < 4; ++f)
#pragma unroll
        for (int r = 0; r < 4; ++r) {
            const int m = m0 + 16 * wv + (ln >> 4) * 4 + r;
            const int n = n0 + f * 16 + (ln & 15);
            epi(m, n, acc[f][r]);
        }
}

// ---------------------------------------------------------------------------
// K1: LayerNorm1 + window partition.  XC:(B,C,H,W) -> XN:(win,n,C)
// ---------------------------------------------------------------------------
__global__ __launch_bounds__(256) void k_ln1(const unsigned short* __restrict__ x,
                                             const unsigned short* __restrict__ g,
                                             const unsigned short* __restrict__ bt,
                                             unsigned short* __restrict__ XN) {
    __shared__ __align__(16) unsigned short xs[256 * 65];
    __shared__ float ps[4][64], ps2[4][64];
    __shared__ float mean_s[64], rstd_s[64];
    const int tid = threadIdx.x;
    const int win = blockIdx.x;
    const int b = win >> 6, wh = (win >> 3) & 7, ww = win & 7;

    for (int idx = tid; idx < 16384; idx += 256) {
        const int c = idx >> 6, n = idx & 63;
        const int h = wh * 8 + (n >> 3), w = ww * 8 + (n & 7);
        xs[c * 65 + n] = x[((size_t)(b * CC + c) * HH + h) * WW2 + w];
    }
    __syncthreads();
    {
        const int tok = tid & 63, part = tid >> 6;
        float s = 0.f, s2 = 0.f;
        for (int c = part * 64; c < part * 64 + 64; ++c) {
            const float v = b2f(xs[c * 65 + tok]);
            s += v; s2 += v * v;
        }
        ps[part][tok] = s; ps2[part][tok] = s2;
    }
    __syncthreads();
    if (tid < 64) {
        const float s  = ps[0][tid] + ps[1][tid] + ps[2][tid] + ps[3][tid];
        const float s2 = ps2[0][tid] + ps2[1][tid] + ps2[2][tid] + ps2[3][tid];
        const float mean = s * (1.f / 256.f);
        const float var  = s2 * (1.f / 256.f) - mean * mean;
        mean_s[tid] = mean;
        rstd_s[tid] = rsqrtf(var + 1e-5f);
    }
    __syncthreads();
    for (int idx = tid; idx < 16384; idx += 256) {
        const int n = idx >> 8, c = idx & 255;
        const float v = (b2f(xs[c * 65 + n]) - mean_s[n]) * rstd_s[n] * b2f(g[c]) + b2f(bt[c]);
        XN[(size_t)(win * NT + n) * CC + c] = f2b(v);
    }
}

// ---------------------------------------------------------------------------
// K2: QKV GEMM -> Q(scaled),K,V  layout [win][head][n][hd]
// ---------------------------------------------------------------------------
__global__ __launch_bounds__(256) void k_gemm_qkv(const unsigned short* __restrict__ XN,
                                                  const unsigned short* __restrict__ Wq,
                                                  const unsigned short* __restrict__ bq,
                                                  unsigned short* __restrict__ Q,
                                                  unsigned short* __restrict__ K,
                                                  unsigned short* __restrict__ V) {
    gemm64<256>(XN, Wq, [&](int m, int n, float v) {
        v += b2f(bq[n]);
        const int three = n >> 8, rem = n & 255, head = rem >> 5, d = rem & 31;
        if (three == 0) v *= 4.0f;   // qk_scale
        unsigned short* dst = (three == 0) ? Q : ((three == 1) ? K : V);
        const int win = m >> 6, nt = m & 63;
        dst[((size_t)(win * NHD + head) * NT + nt) * HD + d] = f2b(v);
    });
}

// ---------------------------------------------------------------------------
// K3: window attention (block per (window, head)); register softmax
// ---------------------------------------------------------------------------
__global__ __launch_bounds__(256) void k_attn(const unsigned short* __restrict__ Q,
                                              const unsigned short* __restrict__ K,
                                              const unsigned short* __restrict__ V,
                                              const unsigned short* __restrict__ rpb,
                                              unsigned short* __restrict__ AO) {
    __shared__ __align__(16) unsigned short Pb[64 * 72];
    __shared__ __align__(16) unsigned short Vt[32 * 72];
    const int tid = threadIdx.x, wv = tid >> 6, ln = tid & 63;
    const int win = blockIdx.x, head = blockIdx.y;
    const size_t base = (size_t)(win * NHD + head) * NT * HD;
    const unsigned short* Qb = Q + base;
    const unsigned short* Kb = K + base;
    const unsigned short* Vb = V + base;

    for (int idx = tid; idx < 2048; idx += 256)
        Vt[(idx & 31) * 72 + (idx >> 5)] = Vb[idx];   // V transposed [d][tok]

    // S = Q K^T   (hd = 32 = one MFMA K-step)
    const bf16x8 a = *(const bf16x8*)&Qb[(16 * wv + (ln & 15)) * HD + (ln >> 4) * 8];
    f32x4 accs[4] = {};
#pragma unroll
    for (int f = 0; f < 4; ++f) {
        const bf16x8 b = *(const bf16x8*)&Kb[(f * 16 + (ln & 15)) * HD + (ln >> 4) * 8];
        accs[f] = __builtin_amdgcn_mfma_f32_16x16x32_bf16(a, b, accs[f], 0, 0, 0);
    }
    const int qloc = (ln >> 4) * 4;
#pragma unroll
    for (int f = 0; f < 4; ++f)
#pragma unroll
        for (int r = 0; r < 4; ++r) {
            const int rr = 16 * wv + qloc + r;
            const int cth = f * 16 + (ln & 15);
            const int bidx = ((rr >> 3) - (cth >> 3) + 7) * 15 + ((rr & 7) - (cth & 7) + 7);
            accs[f][r] += b2f(rpb[bidx * NHD + head]);
        }
#pragma unroll
    for (int r = 0; r < 4; ++r) {
        float m = fmaxf(fmaxf(accs[0][r], accs[1][r]), fmaxf(accs[2][r], accs[3][r]));
#pragma unroll
        for (int o = 1; o <= 8; o <<= 1) m = fmaxf(m, __shfl_xor(m, o));
        float p[4], s = 0.f;
#pragma unroll
        for (int f = 0; f < 4; ++f) { p[f] = expf(accs[f][r] - m); s += p[f]; }
#pragma unroll
        for (int o = 1; o <= 8; o <<= 1) s += __shfl_xor(s, o);
        const float inv = 1.f / s;
#pragma unroll
        for (int f = 0; f < 4; ++f)
            Pb[(16 * wv + qloc + r) * 72 + f * 16 + (ln & 15)] = f2b(p[f] * inv);
    }
    __syncthreads();

    f32x4 acco[2] = {};
#pragma unroll
    for (int kb = 0; kb < 64; kb += 32) {
        const bf16x8 ap = *(const bf16x8*)&Pb[(16 * wv + (ln & 15)) * 72 + kb + (ln >> 4) * 8];
#pragma unroll
        for (int f = 0; f < 2; ++f) {
            const bf16x8 bv = *(const bf16x8*)&Vt[(f * 16 + (ln & 15)) * 72 + kb + (ln >> 4) * 8];
            acco[f] = __builtin_amdgcn_mfma_f32_16x16x32_bf16(ap, bv, acco[f], 0, 0, 0);
        }
    }
#pragma unroll
    for (int f = 0; f < 2; ++f)
#pragma unroll
        for (int r = 0; r < 4; ++r) {
            const int rr = 16 * wv + qloc + r;
            const int d = f * 16 + (ln & 15);
            AO[(size_t)(win * NT + rr) * CC + head * HD + d] = f2b(acco[f][r]);
        }
}

// ---------------------------------------------------------------------------
// K4: gaze depthwise 9x9 — LDS-tiled, register sliding window.
// Block: 16 rows x 8 cols of image pixels x 32 channels (one head), one b.
// grid = (8 colTiles, 4 rowTiles, 128 = b*8+head)
// ---------------------------------------------------------------------------
__global__ __launch_bounds__(256) void k_gaze(const unsigned short* __restrict__ V,
                                              const unsigned short* __restrict__ gw,
                                              const unsigned short* __restrict__ gb,
                                              unsigned short* __restrict__ AO) {
    __shared__ __align__(16) unsigned short ins[24 * 16 * 32];  // [row][col][ch]
    __shared__ __align__(16) unsigned short wlds[81 * 32];      // [k][ch]
    const int tid = threadIdx.x;
    const int c0 = blockIdx.x * 8, r0 = blockIdx.y * 16;
    const int b = blockIdx.z >> 3, head = blockIdx.z & 7;

    // stage halo tile: rows r0-4..r0+19, cols c0-4..c0+11, 32 ch (16B vec loads)
    for (int idx = tid; idx < 1536; idx += 256) {
        const int pix = idx >> 2, v4 = (idx & 3) * 8;
        const int row = pix >> 4, colL = pix & 15;
        const int rp = r0 + row - GPAD, cp = c0 + colL - GPAD;
        uint4 val = {0, 0, 0, 0};
        if (rp >= 0 && rp < HH && cp >= 0 && cp < WW2) {
            const int win = b * 64 + (rp & 7) * 8 + (cp & 7);
            const int n = (rp >> 3) * 8 + (cp >> 3);
            val = *(const uint4*)&V[((size_t)(win * NHD + head) * NT + n) * HD + v4];
        }
        *(uint4*)&ins[(row * 16 + colL) * 32 + v4] = val;
    }
    // stage weights for this head's 32 channels
    for (int idx = tid; idx < 324; idx += 256) {
        const int k = idx >> 2, v4 = (idx & 3) * 8;
        *(uint4*)&wlds[k * 32 + v4] = *(const uint4*)&gw[k * CC + head * HD + v4];
    }
    __syncthreads();

    const int d = tid & 31;         // channel within head
    const int col = tid >> 5;       // 0..7 local output column
    float out[16];
#pragma unroll
    for (int ro = 0; ro < 16; ++ro) out[ro] = 0.f;

#pragma unroll
    for (int dx = 0; dx < GKS; ++dx) {
        float wreg[GKS];
#pragma unroll
        for (int dy = 0; dy < GKS; ++dy)
            wreg[dy] = b2f(wlds[(dy * GKS + dx) * 32 + d]);
        float inreg[24];
#pragma unroll
        for (int ri = 0; ri < 24; ++ri)
            inreg[ri] = b2f(ins[(ri * 16 + col + dx) * 32 + d]);
#pragma unroll
        for (int ro = 0; ro < 16; ++ro)
#pragma unroll
            for (int dy = 0; dy < GKS; ++dy)
                out[ro] = fmaf(inreg[ro + dy], wreg[dy], out[ro]);
    }

    const float bias = b2f(gb[head * HD + d]);
    const int c = c0 + col;
#pragma unroll
    for (int ro = 0; ro < 16; ++ro) {
        const int r = r0 + ro;
        const int win0 = b * 64 + (r & 7) * 8 + (c & 7);
        const int n0 = (r >> 3) * 8 + (c >> 3);
        const size_t o = (size_t)(win0 * NT + n0) * CC + head * HD + d;
        AO[o] = f2b(b2f(AO[o]) + out[ro] + bias);
    }
}

// ---------------------------------------------------------------------------
// K5: proj GEMM + shortcut residual -> X2 (bf16, windowed order)
// ---------------------------------------------------------------------------
__global__ __launch_bounds__(256) void k_gemm_proj(const unsigned short* __restrict__ AO,
                                                   const unsigned short* __restrict__ Wp,
                                                   const unsigned short* __restrict__ bp,
                                                   const unsigned short* __restrict__ XC,
                                                   unsigned short* __restrict__ X2) {
    gemm64<256>(AO, Wp, [&](int m, int n, float v) {
        const int win = m >> 6, nt = m & 63;
        const int b = win >> 6, wh = (win >> 3) & 7, ww = win & 7;
        const int h = wh * 8 + (nt >> 3), w = ww * 8 + (nt & 7);
        v += b2f(bp[n]) + b2f(XC[((size_t)(b * CC + n) * HH + h) * WW2 + w]);
        X2[(size_t)m * CC + n] = f2b(v);
    });
}

// ---------------------------------------------------------------------------
// K6: LayerNorm2 (wave per token)
// ---------------------------------------------------------------------------
__global__ __launch_bounds__(256) void k_ln2(const unsigned short* __restrict__ X2,
                                             const unsigned short* __restrict__ g,
                                             const unsigned short* __restrict__ bt,
                                             unsigned short* __restrict__ X2N) {
    const int wv = threadIdx.x >> 6, ln = threadIdx.x & 63;
    const int t = blockIdx.x * 4 + wv;
    float vals[4];
    float s = 0.f, s2 = 0.f;
#pragma unroll
    for (int k = 0; k < 4; ++k) {
        const float v = b2f(X2[(size_t)t * CC + k * 64 + ln]);
        vals[k] = v; s += v; s2 += v * v;
    }
#pragma unroll
    for (int off = 32; off; off >>= 1) {
        s += __shfl_xor(s, off);
        s2 += __shfl_xor(s2, off);
    }
    const float mean = s * (1.f / 256.f);
    const float rstd = rsqrtf(s2 * (1.f / 256.f) - mean * mean + 1e-5f);
#pragma unroll
    for (int k = 0; k < 4; ++k) {
        const int c = k * 64 + ln;
        X2N[(size_t)t * CC + c] = f2b((vals[k] - mean) * rstd * b2f(g[c]) + b2f(bt[c]));
    }
}

// ---------------------------------------------------------------------------
// K7: fc1 GEMM + exact GELU -> H1
// ---------------------------------------------------------------------------
__global__ __launch_bounds__(256) void k_gemm_fc1(const unsigned short* __restrict__ X2N,
                                                  const unsigned short* __restrict__ W1,
                                                  const unsigned short* __restrict__ b1,
                                                  unsigned short* __restrict__ H1) {
    gemm64<256>(X2N, W1, [&](int m, int n, float v) {
        v += b2f(b1[n]);
        const float gl = 0.5f * v * (1.0f + erff(v * 0.70710678118654752f));
        H1[(size_t)m * HIDN + n] = f2b(gl);
    });
}

// ---------------------------------------------------------------------------
// K8: fc2 GEMM + trunk residual -> XOUT (windowed order)
// ---------------------------------------------------------------------------
__global__ __launch_bounds__(256) void k_gemm_fc2(const unsigned short* __restrict__ H1,
                                                  const unsigned short* __restrict__ W2,
                                                  const unsigned short* __restrict__ b2v,
                                                  const unsigned short* __restrict__ X2,
                                                  unsigned short* __restrict__ XOUT) {
    gemm64<1024>(H1, W2, [&](int m, int n, float v) {
        v += b2f(b2v[n]) + b2f(X2[(size_t)m * CC + n]);
        XOUT[(size_t)m * CC + n] = f2b(v);
    });
}

// ---------------------------------------------------------------------------
// K9: window reverse + transpose to (B,C,H,W); dtype-flagged output store
// ---------------------------------------------------------------------------
__global__ __launch_bounds__(256) void k_out(const unsigned short* __restrict__ XOUT,
                                             const int* __restrict__ flag,
                                             void* __restrict__ out) {
    __shared__ __align__(16) unsigned short ys[64 * 257];
    const int tid = threadIdx.x;
    const int win = blockIdx.x;
    const int b = win >> 6, wh = (win >> 3) & 7, ww = win & 7;
    for (int idx = tid; idx < 16384; idx += 256) {
        const int n = idx >> 8, c = idx & 255;
        ys[n * 257 + c] = XOUT[(size_t)(win * NT + n) * CC + c];
    }
    __syncthreads();
    const bool f32 = (*flag != 0);
    for (int idx = tid; idx < 16384; idx += 256) {
        const int ch = idx >> 6, n = idx & 63;
        const int h = wh * 8 + (n >> 3), w = ww * 8 + (n & 7);
        const size_t o = ((size_t)(b * CC + ch) * HH + h) * WW2 + w;
        const unsigned short v = ys[n * 257 + ch];
        if (f32) ((float*)out)[o] = b2f(v);
        else     ((unsigned short*)out)[o] = v;
    }
}

// ---------------------------------------------------------------------------
extern "C" void kernel_launch(void* const* d_in, const int* in_sizes, int n_in,
                              void* d_out, int out_size, void* d_ws, size_t ws_size,
                              hipStream_t stream) {
    char* ws = (char*)d_ws;
    const size_t MB = 1048576;
    unsigned short* XC  = (unsigned short*)(ws);
    unsigned short* XN  = (unsigned short*)(ws + 32 * MB);
    unsigned short* Qb  = (unsigned short*)(ws + 64 * MB);
    unsigned short* Kb  = (unsigned short*)(ws + 96 * MB);
    unsigned short* Vb  = (unsigned short*)(ws + 128 * MB);
    unsigned short* AO  = (unsigned short*)(ws + 160 * MB);
    unsigned short* H1  = (unsigned short*)(ws + 64 * MB);
    unsigned short* X2  = (unsigned short*)(ws + 192 * MB);
    unsigned short* PAR = (unsigned short*)(ws + 224 * MB);
    int* FLAG = (int*)(ws + 224 * MB);
    unsigned short* X2N  = XN;
    unsigned short* XOUT = XN;

    ParTab tab;
    const int srcidx[15] = {3, 4, 5, 6, 7, 8, 9, 10, 11, 12, 13, 14, 15, 16, 17};
    const int sizes[15]  = {256, 256, 196608, 768, 1800, 65536, 256, 20736, 256,
                            256, 256, 262144, 1024, 262144, 256};
    const int offs[15]   = {O_N1G, O_N1B, O_QKVW, O_QKVB, O_RPB, O_PW, O_PB, O_GW, O_GB,
                            O_N2G, O_N2B, O_W1, O_B1, O_W2, O_B2};
    for (int i = 0; i < 15; ++i) {
        tab.src[i] = d_in[srcidx[i]];
        tab.n[i] = sizes[i];
        tab.off[i] = offs[i];
    }

    k_detect  <<<1,                 256, 0, stream>>>((const unsigned short*)d_in[2], FLAG);
    k_conv_x  <<<8192,              256, 0, stream>>>(d_in[2], FLAG, XC);
    k_conv_par<<<dim3(64, 15),      256, 0, stream>>>(tab, FLAG, PAR);
    k_ln1     <<<NWIN,              256, 0, stream>>>(XC, PAR + O_N1G, PAR + O_N1B, XN);
    k_gemm_qkv<<<dim3(1024, 12),    256, 0, stream>>>(XN, PAR + O_QKVW, PAR + O_QKVB, Qb, Kb, Vb);
    k_attn    <<<dim3(NWIN, NHD),   256, 0, stream>>>(Qb, Kb, Vb, PAR + O_RPB, AO);
    k_gaze    <<<dim3(8, 4, 128),   256, 0, stream>>>(Vb, PAR + O_GW, PAR + O_GB, AO);
    k_gemm_proj<<<dim3(1024, 4),    256, 0, stream>>>(AO, PAR + O_PW, PAR + O_PB, XC, X2);
    k_ln2     <<<TOK / 4,           256, 0, stream>>>(X2, PAR + O_N2G, PAR + O_N2B, X2N);
    k_gemm_fc1<<<dim3(1024, 16),    256, 0, stream>>>(X2N, PAR + O_W1, PAR + O_B1, H1);
    k_gemm_fc2<<<dim3(1024, 4),     256, 0, stream>>>(H1, PAR + O_W2, PAR + O_B2, X2, XOUT);
    k_out     <<<NWIN,              256, 0, stream>>>(XOUT, FLAG, d_out);
}

// Round 4
// 617.833 us; speedup vs baseline: 2.2874x; 1.2328x over previous
//
#include <hip/hip_runtime.h>
#include <math.h>

// ---------- problem constants ----------
#define BB    16
#define CC    256
#define HH    64
#define WW2   64
#define NHD   8
#define HD    32
#define NT    64
#define NWIN  1024
#define TOK   65536
#define HIDN  1024
#define GKS   9
#define GPAD  4

typedef short bf16x8 __attribute__((ext_vector_type(8)));
typedef float f32x4  __attribute__((ext_vector_type(4)));
typedef unsigned short u16x8 __attribute__((ext_vector_type(8)));

__device__ __forceinline__ float b2f(unsigned short u) {
    return __uint_as_float(((unsigned int)u) << 16);
}
__device__ __forceinline__ unsigned short f2b(float f) {
    unsigned int x = __float_as_uint(f);
    unsigned int r = x + 0x7fffu + ((x >> 16) & 1u);   // RNE
    return (unsigned short)(r >> 16);
}

// canonical-param element offsets inside PAR
#define O_N1G  64
#define O_N1B  320
#define O_QKVW 576
#define O_QKVB 197184
#define O_RPB  197952
#define O_PW   199808
#define O_PB   265344
#define O_GW   265600
#define O_GB   286336
#define O_N2G  286592
#define O_N2B  286848
#define O_W1   287104
#define O_B1   549248
#define O_W2   550272
#define O_B2   812416

struct ParTab {
    const void* src[15];
    int n[15];
    int off[15];
};

// ---------------------------------------------------------------------------
// K0: dtype detector (round-2 proved fp32; keep the hedge)
// ---------------------------------------------------------------------------
__global__ __launch_bounds__(256) void k_detect(const unsigned short* __restrict__ x,
                                                int* __restrict__ flag) {
    __shared__ int cnt;
    if (threadIdx.x == 0) cnt = 0;
    __syncthreads();
    const unsigned short u = x[threadIdx.x];
    const int e = (u >> 7) & 0xFF;
    if (e >= 140) atomicAdd(&cnt, 1);
    __syncthreads();
    if (threadIdx.x == 0) *flag = (cnt >= 8) ? 1 : 0;
}

// K0c: canonicalize the 15 parameter tensors into PAR (bf16)
__global__ __launch_bounds__(256) void k_conv_par(ParTab tab,
                                                  const int* __restrict__ flag,
                                                  unsigned short* __restrict__ par) {
    const int t = blockIdx.y;
    const int n = tab.n[t], off = tab.off[t];
    const bool f32 = (*flag != 0);
    for (int i = blockIdx.x * 256 + threadIdx.x; i < n; i += 64 * 256) {
        par[off + i] = f32 ? f2b(((const float*)tab.src[t])[i])
                           : ((const unsigned short*)tab.src[t])[i];
    }
}

// ---------------------------------------------------------------------------
// K1: fused transpose/window-partition + LayerNorm1.
// x:(B,C,H,W) f32|bf16 -> SC (raw bf16, token-major windowed) + XN (normed)
// one block per window
// ---------------------------------------------------------------------------
__global__ __launch_bounds__(256) void k_pre(const void* __restrict__ xsrc,
                                             const int* __restrict__ flag,
                                             const unsigned short* __restrict__ g,
                                             const unsigned short* __restrict__ bt,
                                             unsigned short* __restrict__ SC,
                                             unsigned short* __restrict__ XN) {
    __shared__ __align__(16) unsigned short xs[256 * 65];
    __shared__ float ps[4][64], ps2[4][64];
    __shared__ float mean_s[64], rstd_s[64];
    const int tid = threadIdx.x;
    const int win = blockIdx.x;
    const int b = win >> 6, wh = (win >> 3) & 7, ww = win & 7;
    const bool f32 = (*flag != 0);

    for (int idx = tid; idx < 16384; idx += 256) {
        const int c = idx >> 6, n = idx & 63;
        const int h = wh * 8 + (n >> 3), w = ww * 8 + (n & 7);
        const size_t o = ((size_t)(b * CC + c) * HH + h) * WW2 + w;
        xs[c * 65 + n] = f32 ? f2b(((const float*)xsrc)[o])
                             : ((const unsigned short*)xsrc)[o];
    }
    __syncthreads();
    {
        const int tok = tid & 63, part = tid >> 6;
        float s = 0.f, s2 = 0.f;
        for (int c = part * 64; c < part * 64 + 64; ++c) {
            const float v = b2f(xs[c * 65 + tok]);
            s += v; s2 += v * v;
        }
        ps[part][tok] = s; ps2[part][tok] = s2;
    }
    __syncthreads();
    if (tid < 64) {
        const float s  = ps[0][tid] + ps[1][tid] + ps[2][tid] + ps[3][tid];
        const float s2 = ps2[0][tid] + ps2[1][tid] + ps2[2][tid] + ps2[3][tid];
        const float mean = s * (1.f / 256.f);
        const float var  = s2 * (1.f / 256.f) - mean * mean;
        mean_s[tid] = mean;
        rstd_s[tid] = rsqrtf(var + 1e-5f);
    }
    __syncthreads();
    for (int idx = tid; idx < 16384; idx += 256) {
        const int n = idx >> 8, c = idx & 255;
        const unsigned short raw = xs[c * 65 + n];
        const float v = (b2f(raw) - mean_s[n]) * rstd_s[n] * b2f(g[c]) + b2f(bt[c]);
        const size_t o = (size_t)(win * NT + n) * CC + c;
        SC[o] = raw;
        XN[o] = f2b(v);
    }
}

// ---------------------------------------------------------------------------
// 128x128-tile MFMA GEMM core (m97 structure): C[m][n] = sum_k A[m][k]*B[n][k]
// global_load_lds staging (16B), 4 waves each 64x64, LDS epilogue for
// coalesced 16B stores. pre: scalar pre-op; post8: vectorized store.
// ---------------------------------------------------------------------------
template <int KDIM, typename PreF, typename PostF>
__device__ __forceinline__ void gemm128(const unsigned short* __restrict__ A,
                                        const unsigned short* __restrict__ Bw,
                                        PreF pre, PostF post8) {
    __shared__ __align__(16) unsigned short smem[128 * 136];   // 34 KB
    unsigned short* As = smem;            // [128][64]
    unsigned short* Bs = smem + 8192;     // [128][64]
    const int tid = threadIdx.x;
    const int wv = tid >> 6, ln = tid & 63;
    const int wm = wv & 1, wn = wv >> 1;
    const int m0 = blockIdx.x * 128, n0 = blockIdx.y * 128;

    f32x4 acc[4][4] = {};

    const int u = tid;                    // staging unit id base
    const int arow = u >> 3, ac8 = (u & 7) * 8;

    for (int kb = 0; kb < KDIM; kb += 64) {
#pragma unroll
        for (int i = 0; i < 4; ++i) {
            const int uu = i * 256 + u;
            const int row = uu >> 3, c8 = (uu & 7) * 8;
            __builtin_amdgcn_global_load_lds(
                (const __attribute__((address_space(1))) unsigned int*)
                    &A[(size_t)(m0 + row) * KDIM + kb + c8],
                (__attribute__((address_space(3))) unsigned int*)&As[uu * 8],
                16, 0, 0);
            __builtin_amdgcn_global_load_lds(
                (const __attribute__((address_space(1))) unsigned int*)
                    &Bw[(size_t)(n0 + row) * KDIM + kb + c8],
                (__attribute__((address_space(3))) unsigned int*)&Bs[uu * 8],
                16, 0, 0);
        }
        __syncthreads();
#pragma unroll
        for (int ks = 0; ks < 2; ++ks) {
            bf16x8 af[4], bf[4];
#pragma unroll
            for (int t = 0; t < 4; ++t) {
                af[t] = *(const bf16x8*)&As[(wm * 64 + t * 16 + (ln & 15)) * 64 + ks * 32 + (ln >> 4) * 8];
                bf[t] = *(const bf16x8*)&Bs[(wn * 64 + t * 16 + (ln & 15)) * 64 + ks * 32 + (ln >> 4) * 8];
            }
#pragma unroll
            for (int mt = 0; mt < 4; ++mt)
#pragma unroll
                for (int nt = 0; nt < 4; ++nt)
                    acc[mt][nt] = __builtin_amdgcn_mfma_f32_16x16x32_bf16(af[mt], bf[nt], acc[mt][nt], 0, 0, 0);
        }
        __syncthreads();
    }
    (void)arow; (void)ac8;

    // epilogue: pre-op -> bf16 stage in LDS (rows padded to 136) -> 16B stores
    unsigned short* Cs = smem;
#pragma unroll
    for (int mt = 0; mt < 4; ++mt)
#pragma unroll
        for (int nt = 0; nt < 4; ++nt)
#pragma unroll
            for (int r = 0; r < 4; ++r) {
                const int ml = wm * 64 + mt * 16 + (ln >> 4) * 4 + r;
                const int nl = wn * 64 + nt * 16 + (ln & 15);
                Cs[ml * 136 + nl] = f2b(pre(m0 + ml, n0 + nl, acc[mt][nt][r]));
            }
    __syncthreads();
#pragma unroll
    for (int i = 0; i < 8; ++i) {
        const int j = i * 256 + tid;
        const int row = j >> 4, c8 = (j & 15) * 8;
        const u16x8 vals = *(const u16x8*)&Cs[row * 136 + c8];
        post8(m0 + row, n0 + c8, vals);
    }
}

// ---------------------------------------------------------------------------
// K2: QKV GEMM -> Q(scaled),K,V  token-major [65536][256]
// ---------------------------------------------------------------------------
__global__ __launch_bounds__(256) void k_gemm_qkv(const unsigned short* __restrict__ XN,
                                                  const unsigned short* __restrict__ Wq,
                                                  const unsigned short* __restrict__ bq,
                                                  unsigned short* __restrict__ Q,
                                                  unsigned short* __restrict__ K,
                                                  unsigned short* __restrict__ V) {
    gemm128<256>(XN, Wq,
        [&](int m, int n, float v) {
            v += b2f(bq[n]);
            return (n < 256) ? v * 4.0f : v;
        },
        [&](int m, int nb, u16x8 vals) {
            unsigned short* dst = (nb < 256) ? Q : ((nb < 512) ? K : V);
            *(u16x8*)&dst[(size_t)m * CC + (nb & 255)] = vals;
        });
}

// ---------------------------------------------------------------------------
// K3: window attention (block per (window, head)); Q/K/V token-major
// ---------------------------------------------------------------------------
__global__ __launch_bounds__(256) void k_attn(const unsigned short* __restrict__ Q,
                                              const unsigned short* __restrict__ K,
                                              const unsigned short* __restrict__ V,
                                              const unsigned short* __restrict__ rpb,
                                              unsigned short* __restrict__ AO) {
    __shared__ __align__(16) unsigned short Pb[64 * 72];
    __shared__ __align__(16) unsigned short Vt[32 * 72];
    const int tid = threadIdx.x, wv = tid >> 6, ln = tid & 63;
    const int win = blockIdx.x, head = blockIdx.y;
    const size_t tbase = (size_t)(win * NT) * CC + head * HD;

    for (int idx = tid; idx < 2048; idx += 256) {
        const int tok = idx >> 5, d = idx & 31;
        Vt[d * 72 + tok] = V[tbase + (size_t)tok * CC + d];
    }

    const bf16x8 a = *(const bf16x8*)&Q[tbase + (size_t)(16 * wv + (ln & 15)) * CC + (ln >> 4) * 8];
    f32x4 accs[4] = {};
#pragma unroll
    for (int f = 0; f < 4; ++f) {
        const bf16x8 b = *(const bf16x8*)&K[tbase + (size_t)(f * 16 + (ln & 15)) * CC + (ln >> 4) * 8];
        accs[f] = __builtin_amdgcn_mfma_f32_16x16x32_bf16(a, b, accs[f], 0, 0, 0);
    }
    const int qloc = (ln >> 4) * 4;
#pragma unroll
    for (int f = 0; f < 4; ++f)
#pragma unroll
        for (int r = 0; r < 4; ++r) {
            const int rr = 16 * wv + qloc + r;
            const int cth = f * 16 + (ln & 15);
            const int bidx = ((rr >> 3) - (cth >> 3) + 7) * 15 + ((rr & 7) - (cth & 7) + 7);
            accs[f][r] += b2f(rpb[bidx * NHD + head]);
        }
#pragma unroll
    for (int r = 0; r < 4; ++r) {
        float m = fmaxf(fmaxf(accs[0][r], accs[1][r]), fmaxf(accs[2][r], accs[3][r]));
#pragma unroll
        for (int o = 1; o <= 8; o <<= 1) m = fmaxf(m, __shfl_xor(m, o));
        float p[4], s = 0.f;
#pragma unroll
        for (int f = 0; f < 4; ++f) { p[f] = expf(accs[f][r] - m); s += p[f]; }
#pragma unroll
        for (int o = 1; o <= 8; o <<= 1) s += __shfl_xor(s, o);
        const float inv = 1.f / s;
#pragma unroll
        for (int f = 0; f < 4; ++f)
            Pb[(16 * wv + qloc + r) * 72 + f * 16 + (ln & 15)] = f2b(p[f] * inv);
    }
    __syncthreads();

    f32x4 acco[2] = {};
#pragma unroll
    for (int kb = 0; kb < 64; kb += 32) {
        const bf16x8 ap = *(const bf16x8*)&Pb[(16 * wv + (ln & 15)) * 72 + kb + (ln >> 4) * 8];
#pragma unroll
        for (int f = 0; f < 2; ++f) {
            const bf16x8 bv = *(const bf16x8*)&Vt[(f * 16 + (ln & 15)) * 72 + kb + (ln >> 4) * 8];
            acco[f] = __builtin_amdgcn_mfma_f32_16x16x32_bf16(ap, bv, acco[f], 0, 0, 0);
        }
    }
#pragma unroll
    for (int f = 0; f < 2; ++f)
#pragma unroll
        for (int r = 0; r < 4; ++r) {
            const int rr = 16 * wv + qloc + r;
            const int d = f * 16 + (ln & 15);
            AO[tbase + (size_t)rr * CC + d] = f2b(acco[f][r]);
        }
}

// ---------------------------------------------------------------------------
// K4: gaze depthwise 9x9 — LDS-tiled register sliding window (V token-major)
// ---------------------------------------------------------------------------
__global__ __launch_bounds__(256) void k_gaze(const unsigned short* __restrict__ V,
                                              const unsigned short* __restrict__ gw,
                                              const unsigned short* __restrict__ gb,
                                              unsigned short* __restrict__ AO) {
    __shared__ __align__(16) unsigned short ins[24 * 16 * 32];
    __shared__ __align__(16) unsigned short wlds[81 * 32];
    const int tid = threadIdx.x;
    const int c0 = blockIdx.x * 8, r0 = blockIdx.y * 16;
    const int b = blockIdx.z >> 3, head = blockIdx.z & 7;

    for (int idx = tid; idx < 1536; idx += 256) {
        const int pix = idx >> 2, v4 = (idx & 3) * 8;
        const int row = pix >> 4, colL = pix & 15;
        const int rp = r0 + row - GPAD, cp = c0 + colL - GPAD;
        uint4 val = {0, 0, 0, 0};
        if (rp >= 0 && rp < HH && cp >= 0 && cp < WW2) {
            const int win = b * 64 + (rp & 7) * 8 + (cp & 7);
            const int n = (rp >> 3) * 8 + (cp >> 3);
            val = *(const uint4*)&V[(size_t)(win * NT + n) * CC + head * HD + v4];
        }
        *(uint4*)&ins[(row * 16 + colL) * 32 + v4] = val;
    }
    for (int idx = tid; idx < 324; idx += 256) {
        const int k = idx >> 2, v4 = (idx & 3) * 8;
        *(uint4*)&wlds[k * 32 + v4] = *(const uint4*)&gw[k * CC + head * HD + v4];
    }
    __syncthreads();

    const int d = tid & 31;
    const int col = tid >> 5;
    float out[16];
#pragma unroll
    for (int ro = 0; ro < 16; ++ro) out[ro] = 0.f;

#pragma unroll
    for (int dx = 0; dx < GKS; ++dx) {
        float wreg[GKS];
#pragma unroll
        for (int dy = 0; dy < GKS; ++dy)
            wreg[dy] = b2f(wlds[(dy * GKS + dx) * 32 + d]);
        float inreg[24];
#pragma unroll
        for (int ri = 0; ri < 24; ++ri)
            inreg[ri] = b2f(ins[(ri * 16 + col + dx) * 32 + d]);
#pragma unroll
        for (int ro = 0; ro < 16; ++ro)
#pragma unroll
            for (int dy = 0; dy < GKS; ++dy)
                out[ro] = fmaf(inreg[ro + dy], wreg[dy], out[ro]);
    }

    const float bias = b2f(gb[head * HD + d]);
    const int c = c0 + col;
#pragma unroll
    for (int ro = 0; ro < 16; ++ro) {
        const int r = r0 + ro;
        const int win0 = b * 64 + (r & 7) * 8 + (c & 7);
        const int n0 = (r >> 3) * 8 + (c >> 3);
        const size_t o = (size_t)(win0 * NT + n0) * CC + head * HD + d;
        AO[o] = f2b(b2f(AO[o]) + out[ro] + bias);
    }
}

// ---------------------------------------------------------------------------
// K5: proj GEMM + shortcut residual (SC, coalesced) -> X2 bf16
// ---------------------------------------------------------------------------
__global__ __launch_bounds__(256) void k_gemm_proj(const unsigned short* __restrict__ AO,
                                                   const unsigned short* __restrict__ Wp,
                                                   const unsigned short* __restrict__ bp,
                                                   const unsigned short* __restrict__ SC,
                                                   unsigned short* __restrict__ X2) {
    gemm128<256>(AO, Wp,
        [&](int m, int n, float v) { return v + b2f(bp[n]); },
        [&](int m, int nb, u16x8 vals) {
            const u16x8 sc = *(const u16x8*)&SC[(size_t)m * CC + nb];
            u16x8 o;
#pragma unroll
            for (int j = 0; j < 8; ++j) o[j] = f2b(b2f(vals[j]) + b2f(sc[j]));
            *(u16x8*)&X2[(size_t)m * CC + nb] = o;
        });
}

// ---------------------------------------------------------------------------
// K6: LayerNorm2 (wave per token)
// ---------------------------------------------------------------------------
__global__ __launch_bounds__(256) void k_ln2(const unsigned short* __restrict__ X2,
                                             const unsigned short* __restrict__ g,
                                             const unsigned short* __restrict__ bt,
                                             unsigned short* __restrict__ X2N) {
    const int wv = threadIdx.x >> 6, ln = threadIdx.x & 63;
    const int t = blockIdx.x * 4 + wv;
    float vals[4];
    float s = 0.f, s2 = 0.f;
#pragma unroll
    for (int k = 0; k < 4; ++k) {
        const float v = b2f(X2[(size_t)t * CC + k * 64 + ln]);
        vals[k] = v; s += v; s2 += v * v;
    }
#pragma unroll
    for (int off = 32; off; off >>= 1) {
        s += __shfl_xor(s, off);
        s2 += __shfl_xor(s2, off);
    }
    const float mean = s * (1.f / 256.f);
    const float rstd = rsqrtf(s2 * (1.f / 256.f) - mean * mean + 1e-5f);
#pragma unroll
    for (int k = 0; k < 4; ++k) {
        const int c = k * 64 + ln;
        X2N[(size_t)t * CC + c] = f2b((vals[k] - mean) * rstd * b2f(g[c]) + b2f(bt[c]));
    }
}

// ---------------------------------------------------------------------------
// K7: fc1 GEMM + exact GELU -> H1
// ---------------------------------------------------------------------------
__global__ __launch_bounds__(256) void k_gemm_fc1(const unsigned short* __restrict__ X2N,
                                                  const unsigned short* __restrict__ W1,
                                                  const unsigned short* __restrict__ b1,
                                                  unsigned short* __restrict__ H1) {
    gemm128<256>(X2N, W1,
        [&](int m, int n, float v) {
            v += b2f(b1[n]);
            return 0.5f * v * (1.0f + erff(v * 0.70710678118654752f));
        },
        [&](int m, int nb, u16x8 vals) {
            *(u16x8*)&H1[(size_t)m * HIDN + nb] = vals;
        });
}

// ---------------------------------------------------------------------------
// K8: fc2 GEMM + trunk residual -> XOUT
// ---------------------------------------------------------------------------
__global__ __launch_bounds__(256) void k_gemm_fc2(const unsigned short* __restrict__ H1,
                                                  const unsigned short* __restrict__ W2,
                                                  const unsigned short* __restrict__ b2v,
                                                  const unsigned short* __restrict__ X2,
                                                  unsigned short* __restrict__ XOUT) {
    gemm128<1024>(H1, W2,
        [&](int m, int n, float v) { return v + b2f(b2v[n]); },
        [&](int m, int nb, u16x8 vals) {
            const u16x8 r = *(const u16x8*)&X2[(size_t)m * CC + nb];
            u16x8 o;
#pragma unroll
            for (int j = 0; j < 8; ++j) o[j] = f2b(b2f(vals[j]) + b2f(r[j]));
            *(u16x8*)&XOUT[(size_t)m * CC + nb] = o;
        });
}

// ---------------------------------------------------------------------------
// K9: window reverse + transpose to (B,C,H,W); dtype-flagged output store
// ---------------------------------------------------------------------------
__global__ __launch_bounds__(256) void k_out(const unsigned short* __restrict__ XOUT,
                                             const int* __restrict__ flag,
                                             void* __restrict__ out) {
    __shared__ __align__(16) unsigned short ys[64 * 257];
    const int tid = threadIdx.x;
    const int win = blockIdx.x;
    const int b = win >> 6, wh = (win >> 3) & 7, ww = win & 7;
    for (int idx = tid; idx < 16384; idx += 256) {
        const int n = idx >> 8, c = idx & 255;
        ys[n * 257 + c] = XOUT[(size_t)(win * NT + n) * CC + c];
    }
    __syncthreads();
    const bool f32 = (*flag != 0);
    for (int idx = tid; idx < 16384; idx += 256) {
        const int ch = idx >> 6, n = idx & 63;
        const int h = wh * 8 + (n >> 3), w = ww * 8 + (n & 7);
        const size_t o = ((size_t)(b * CC + ch) * HH + h) * WW2 + w;
        const unsigned short v = ys[n * 257 + ch];
        if (f32) ((float*)out)[o] = b2f(v);
        else     ((unsigned short*)out)[o] = v;
    }
}

// ---------------------------------------------------------------------------
extern "C" void kernel_launch(void* const* d_in, const int* in_sizes, int n_in,
                              void* d_out, int out_size, void* d_ws, size_t ws_size,
                              hipStream_t stream) {
    // workspace (226 MiB):
    //   [0,32)   SC (raw bf16, token-major)      alive through proj
    //   [32,64)  XN -> X2N -> XOUT
    //   [64,96)  Q   ┐
    //   [96,128) K   │ H1 (128M) overlays [64,192) after proj
    //   [128,160) V  │
    //   [160,192) AO ┘
    //   [192,224) X2
    //   [224,226) PAR/flag
    char* ws = (char*)d_ws;
    const size_t MB = 1048576;
    unsigned short* SC  = (unsigned short*)(ws);
    unsigned short* XN  = (unsigned short*)(ws + 32 * MB);
    unsigned short* Qb  = (unsigned short*)(ws + 64 * MB);
    unsigned short* Kb  = (unsigned short*)(ws + 96 * MB);
    unsigned short* Vb  = (unsigned short*)(ws + 128 * MB);
    unsigned short* AO  = (unsigned short*)(ws + 160 * MB);
    unsigned short* H1  = (unsigned short*)(ws + 64 * MB);
    unsigned short* X2  = (unsigned short*)(ws + 192 * MB);
    unsigned short* PAR = (unsigned short*)(ws + 224 * MB);
    int* FLAG = (int*)(ws + 224 * MB);
    unsigned short* X2N  = XN;
    unsigned short* XOUT = XN;

    ParTab tab;
    const int srcidx[15] = {3, 4, 5, 6, 7, 8, 9, 10, 11, 12, 13, 14, 15, 16, 17};
    const int sizes[15]  = {256, 256, 196608, 768, 1800, 65536, 256, 20736, 256,
                            256, 256, 262144, 1024, 262144, 256};
    const int offs[15]   = {O_N1G, O_N1B, O_QKVW, O_QKVB, O_RPB, O_PW, O_PB, O_GW, O_GB,
                            O_N2G, O_N2B, O_W1, O_B1, O_W2, O_B2};
    for (int i = 0; i < 15; ++i) {
        tab.src[i] = d_in[srcidx[i]];
        tab.n[i] = sizes[i];
        tab.off[i] = offs[i];
    }

    k_detect   <<<1,                 256, 0, stream>>>((const unsigned short*)d_in[2], FLAG);
    k_conv_par <<<dim3(64, 15),      256, 0, stream>>>(tab, FLAG, PAR);
    k_pre      <<<NWIN,              256, 0, stream>>>(d_in[2], FLAG, PAR + O_N1G, PAR + O_N1B, SC, XN);
    k_gemm_qkv <<<dim3(512, 6),      256, 0, stream>>>(XN, PAR + O_QKVW, PAR + O_QKVB, Qb, Kb, Vb);
    k_attn     <<<dim3(NWIN, NHD),   256, 0, stream>>>(Qb, Kb, Vb, PAR + O_RPB, AO);
    k_gaze     <<<dim3(8, 4, 128),   256, 0, stream>>>(Vb, PAR + O_GW, PAR + O_GB, AO);
    k_gemm_proj<<<dim3(512, 2),      256, 0, stream>>>(AO, PAR + O_PW, PAR + O_PB, SC, X2);
    k_ln2      <<<TOK / 4,           256, 0, stream>>>(X2, PAR + O_N2G, PAR + O_N2B, X2N);
    k_gemm_fc1 <<<dim3(512, 8),      256, 0, stream>>>(X2N, PAR + O_W1, PAR + O_B1, H1);
    k_gemm_fc2 <<<dim3(512, 2),      256, 0, stream>>>(H1, PAR + O_W2, PAR + O_B2, X2, XOUT);
    k_out      <<<NWIN,              256, 0, stream>>>(XOUT, FLAG, d_out);
}